// Round 5
// baseline (480.522 us; speedup 1.0000x reference)
//
#include <hip/hip_runtime.h>

#define EDGES 1000000
#define NODES 100000
#define ET 128   // edges per tile
#define NB 64    // nodes per block (node_kernel)
#define NBLK ((NODES + NB - 1) / NB)  // 1563
#define NBW ((NODES + 127) / 128)     // 782 wpos blocks

typedef short short8 __attribute__((ext_vector_type(8)));
typedef float floatx4 __attribute__((ext_vector_type(4)));
typedef unsigned int u32x2 __attribute__((ext_vector_type(2)));
typedef unsigned int u32x4 __attribute__((ext_vector_type(4)));

#define MFMA(a, b, c) __builtin_amdgcn_mfma_f32_16x16x32_bf16(a, b, c, 0, 0, 0)

// ws layout (bytes)
#define WS_WX1 0        // 32768: Wx1 bf16 frags
#define WS_WX2 32768    // 16384: Wx2 frags
#define WS_WP1 49152    // 16384: Wp1 frags
#define WS_MISC 65536   // 2048: biases etc (floats)
#define WS_OFF 68608    // off[100128] int = 400512 B (CSR offsets, padded)
#define WS_CNT 469504   // counts/cursor[100000] int = 400000 B (aliased)
#define WS_SREC 917504  // u32[EDGES] = 4 MB packed sorted records (lc<<17|r)
#define WS_POSW 8917504 // float4[NODES] = 1.6 MB {pos.xyz, w_pos} per node
// scan temporaries alias the srec region (they die before scatter writes srec):
#define WS_TMP WS_SREC                 // int[100352] inclusive per-block scans
#define WS_BSUM (WS_SREC + 401408)     // int[98] block sums

__device__ __forceinline__ unsigned short f2bf(float f) {
  union { float f; unsigned int u; } c;
  c.f = f;
  unsigned int u = c.u;
  u += 0x7fffu + ((u >> 16) & 1u);
  return (unsigned short)(u >> 16);
}

__device__ __forceinline__ unsigned int pack2bf(float lo, float hi) {
  return (unsigned int)f2bf(lo) | ((unsigned int)f2bf(hi) << 16);
}

// single-instruction RNE pack (same rounding as f2bf); no builtin on gfx950
__device__ __forceinline__ unsigned int cvtpk2bf(float lo, float hi) {
  unsigned int r;
  asm("v_cvt_pk_bf16_f32 %0, %1, %2" : "=v"(r) : "v"(lo), "v"(hi));
  return r;
}

__device__ __forceinline__ float fast_silu(float v) {
#if __has_builtin(__builtin_amdgcn_exp2f) && __has_builtin(__builtin_amdgcn_rcpf)
  float e = __builtin_amdgcn_exp2f(-1.44269504088896340736f * v);
  return v * __builtin_amdgcn_rcpf(1.0f + e);
#else
  return v / (1.0f + __expf(-v));
#endif
}

// DPP cross-lane within 16-lane rows. row_shr:N = lane i reads lane i-N.
// MUST be called unconditionally in straight-line code (convergent ops).
template <int CTRL>
__device__ __forceinline__ int dpp_i(int v) {
  return __builtin_amdgcn_update_dpp(0, v, CTRL, 0xf, 0xf, true);
}
template <int CTRL>
__device__ __forceinline__ float dpp_f(float v) {
  return __builtin_bit_cast(float, dpp_i<CTRL>(__builtin_bit_cast(int, v)));
}

// Segmented inclusive prefix-sum across nn (16-lane row), segments = runs of
// equal sorted keys; masks m1..m8 from unconditional key equality at d=1,2,4,8.
__device__ __forceinline__ float segscan(float v, bool m1, bool m2, bool m4, bool m8) {
  float t;
  t = dpp_f<0x111>(v); v += m1 ? t : 0.f;
  t = dpp_f<0x112>(v); v += m2 ? t : 0.f;
  t = dpp_f<0x114>(v); v += m4 ? t : 0.f;
  t = dpp_f<0x118>(v); v += m8 ? t : 0.f;
  return v;
}

__device__ __forceinline__ void lds_add(float* p, float v) {
  __hip_atomic_fetch_add(p, v, __ATOMIC_RELAXED, __HIP_MEMORY_SCOPE_WORKGROUP);
}

// prep also zero-inits counts (folds the old hipMemsetAsync launch in; hist
// runs after prep on the same stream)
__global__ __launch_bounds__(256) void prep_kernel(
    const float* __restrict__ Wx1, const float* __restrict__ Wx2,
    const float* __restrict__ Wp1, const float* __restrict__ bx1,
    const float* __restrict__ bx2, const float* __restrict__ bp1,
    const float* __restrict__ Wp2, const float* __restrict__ bp2,
    unsigned char* __restrict__ ws) {
  const int t = blockIdx.x * 256 + threadIdx.x;
  const int nthr = gridDim.x * 256;

  int* counts = (int*)(ws + WS_CNT);
  for (int i = t; i < NODES; i += nthr) counts[i] = 0;

  for (int task = t; task < 2048; task += nthr) {  // Wx1[0:128][0:128]
    const int n = task & 127;
    const int kb = task >> 7;
    const int k0 = kb << 3;
    unsigned int d[4];
#pragma unroll
    for (int i = 0; i < 4; ++i)
      d[i] = pack2bf(Wx1[(k0 + 2 * i) * 128 + n], Wx1[(k0 + 2 * i + 1) * 128 + n]);
    const int lane = ((kb & 3) << 4) | (n & 15);
    const int frag = ((kb >> 2) << 3) | (n >> 4);
    *(uint4*)(ws + WS_WX1 + ((size_t)(frag * 64 + lane) << 4)) =
        make_uint4(d[0], d[1], d[2], d[3]);
  }
  for (int task = t; task < 1024; task += nthr) {  // Wx2[0:128][0:64]
    const int n = task & 63;
    const int kb = task >> 6;
    const int k0 = kb << 3;
    unsigned int d[4];
#pragma unroll
    for (int i = 0; i < 4; ++i)
      d[i] = pack2bf(Wx2[(k0 + 2 * i) * 64 + n], Wx2[(k0 + 2 * i + 1) * 64 + n]);
    const int lane = ((kb & 3) << 4) | (n & 15);
    const int frag = ((kb >> 2) << 2) | (n >> 4);
    *(uint4*)(ws + WS_WX2 + ((size_t)(frag * 64 + lane) << 4)) =
        make_uint4(d[0], d[1], d[2], d[3]);
  }
  for (int task = t; task < 1024; task += nthr) {  // Wp1[0:64][0:128]
    const int n = task & 127;
    const int kb = task >> 7;
    const int k0 = kb << 3;
    unsigned int d[4];
#pragma unroll
    for (int i = 0; i < 4; ++i)
      d[i] = pack2bf(Wp1[(k0 + 2 * i) * 128 + n], Wp1[(k0 + 2 * i + 1) * 128 + n]);
    const int lane = ((kb & 3) << 4) | (n & 15);
    const int frag = ((kb >> 2) << 3) | (n >> 4);
    *(uint4*)(ws + WS_WP1 + ((size_t)(frag * 64 + lane) << 4)) =
        make_uint4(d[0], d[1], d[2], d[3]);
  }
  float* misc = (float*)(ws + WS_MISC);
  for (int i = t; i < 128; i += nthr) misc[i] = bx1[i];
  for (int i = t; i < 64; i += nthr) misc[128 + i] = bx2[i];
  for (int i = t; i < 128; i += nthr) misc[192 + i] = bp1[i];
  for (int i = t; i < 128; i += nthr) misc[320 + i] = Wp2[i];
  if (t == 0) misc[448] = bp2[0];
  for (int i = t; i < 128; i += nthr) misc[456 + i] = Wx1[128 * 128 + i];
}

// ---- per-NODE phi_pos precompute (R12) ----
__global__ __launch_bounds__(256) void wpos_kernel(
    const float* __restrict__ x, const float* __restrict__ pos,
    unsigned char* __restrict__ ws) {
  const uint4* wp1f = (const uint4*)(ws + WS_WP1);
  const float* misc = (const float*)(ws + WS_MISC);
  float* posw = (float*)(ws + WS_POSW);

  const int tid = threadIdx.x;
  const int lane = tid & 63;
  const int wave = tid >> 6;
  const int q = lane >> 4;
  const int nn = lane & 15;
  const int base = blockIdx.x * 128 + wave * 32;  // this wave: nodes base..base+31

  short8 bf[2][2];
#pragma unroll
  for (int m = 0; m < 2; ++m) {
    int node = base + m * 16 + nn;
    node = node < NODES ? node : NODES - 1;
#pragma unroll
    for (int kt = 0; kt < 2; ++kt) {
      const int k0 = kt * 32 + q * 8;
      const float4 a = *(const float4*)(x + (size_t)node * 64 + k0);
      const float4 b = *(const float4*)(x + (size_t)node * 64 + k0 + 4);
      u32x4 d;
      d[0] = cvtpk2bf(a.x, a.y);
      d[1] = cvtpk2bf(a.z, a.w);
      d[2] = cvtpk2bf(b.x, b.y);
      d[3] = cvtpk2bf(b.z, b.w);
      bf[m][kt] = __builtin_bit_cast(short8, d);
    }
  }

  const floatx4 fzero = {0.f, 0.f, 0.f, 0.f};
  floatx4 accp[2][8];
#pragma unroll
  for (int m = 0; m < 2; ++m)
#pragma unroll
    for (int j = 0; j < 8; ++j) accp[m][j] = fzero;
#pragma unroll 1
  for (int kt = 0; kt < 2; ++kt) {
#pragma unroll
    for (int jt = 0; jt < 8; ++jt) {
      const short8 a = __builtin_bit_cast(short8, wp1f[(kt * 8 + jt) * 64 + lane]);
      accp[0][jt] = MFMA(a, bf[0][kt], accp[0][jt]);
      accp[1][jt] = MFMA(a, bf[1][kt], accp[1][jt]);
    }
  }
#pragma unroll
  for (int m = 0; m < 2; ++m) {
    float s = 0.f;
#pragma unroll
    for (int jt = 0; jt < 8; ++jt) {
      const float4 bp = *(const float4*)(misc + 192 + jt * 16 + q * 4);
      const float4 wp = *(const float4*)(misc + 320 + jt * 16 + q * 4);
      s += fast_silu(accp[m][jt][0] + bp.x) * wp.x;
      s += fast_silu(accp[m][jt][1] + bp.y) * wp.y;
      s += fast_silu(accp[m][jt][2] + bp.z) * wp.z;
      s += fast_silu(accp[m][jt][3] + bp.w) * wp.w;
    }
    s += __shfl_xor(s, 16);
    s += __shfl_xor(s, 32);
    const int node = base + m * 16 + nn;
    if (q == 0 && node < NODES) {
      float4 o;
      o.x = pos[3 * node + 0];
      o.y = pos[3 * node + 1];
      o.z = pos[3 * node + 2];
      o.w = s + misc[448];
      *(float4*)(posw + 4 * (size_t)node) = o;
    }
  }
}

// ---- counting sort by col ----
__global__ __launch_bounds__(256) void hist_kernel(const int* __restrict__ ei,
                                                   int* __restrict__ counts) {
  const int t = blockIdx.x * 256 + threadIdx.x;
  if (t < EDGES) {
    int c = __builtin_nontemporal_load(ei + EDGES + t);
    c = (c < 0) ? 0 : ((c >= NODES) ? NODES - 1 : c);
    atomicAdd(&counts[c], 1);
  }
}

#define SCB 98  // blocks of 1024: 98*1024 = 100352 >= NODES+128

__global__ __launch_bounds__(1024) void scan1_kernel(const int* __restrict__ counts,
                                                     int* __restrict__ tmp,
                                                     int* __restrict__ bsum) {
  __shared__ int part[1024];
  const int t = threadIdx.x;
  const int i = blockIdx.x * 1024 + t;
  int v = (i < NODES) ? counts[i] : 0;
  part[t] = v;
  __syncthreads();
  for (int d = 1; d < 1024; d <<= 1) {
    int u = 0;
    if (t >= d) u = part[t - d];
    __syncthreads();
    if (t >= d) part[t] += u;
    __syncthreads();
  }
  tmp[i] = part[t];  // inclusive scan within block
  if (t == 1023) bsum[blockIdx.x] = part[1023];
}

// scan2 merged in — each block re-scans the 98 block sums in LDS
// (tiny log-scan) and picks its exclusive prefix; kills one launch + bsumx.
__global__ __launch_bounds__(1024) void scan3_kernel(const int* __restrict__ counts,
                                                     const int* __restrict__ tmp,
                                                     const int* __restrict__ bsum,
                                                     int* __restrict__ off,
                                                     int* __restrict__ cursor) {
  __shared__ int sb[128];
  const int t = threadIdx.x;
  if (t < 128) sb[t] = (t < SCB) ? bsum[t] : 0;
  __syncthreads();
  for (int d = 1; d < 128; d <<= 1) {
    int u = 0;
    if (t >= d && t < 128) u = sb[t - d];
    __syncthreads();
    if (t >= d && t < 128) sb[t] += u;
    __syncthreads();
  }
  const int bx = (blockIdx.x == 0) ? 0 : sb[blockIdx.x - 1];  // exclusive
  const int i = blockIdx.x * 1024 + t;
  if (i < NODES) {
    const int cn = counts[i];  // read before cursor write (aliased with counts)
    const int o = bx + tmp[i] - cn;
    off[i] = o;
    cursor[i] = o;
  } else if (i < NODES + 128) {
    off[i] = EDGES;
  }
}

// packed record — lc = c & 63 is exact (node_kernel block base is
// (c>>6)*64), r < 2^17. One u32 per edge: halves scatter writes + node reads.
__global__ __launch_bounds__(256) void scatter_kernel(const int* __restrict__ ei,
                                                      int* __restrict__ cursor,
                                                      unsigned int* __restrict__ srec) {
  const int t = blockIdx.x * 256 + threadIdx.x;
  if (t < EDGES) {
    int r = __builtin_nontemporal_load(ei + t);
    int c = __builtin_nontemporal_load(ei + EDGES + t);
    r = (r < 0) ? 0 : ((r >= NODES) ? NODES - 1 : r);
    c = (c < 0) ? 0 : ((c >= NODES) ? NODES - 1 : c);
    const int p = atomicAdd(&cursor[c], 1);
    __builtin_nontemporal_store(((unsigned)(c & 63) << 17) | (unsigned)r, srec + p);
  }
}

// ---- main: node-centric, zero global atomics, zero in-loop barriers ----
// R14: full cross-tile software pipeline within the register budget
// (R10 lesson: demand was ~220 regs and spilled; budget for 3 waves/SIMD is
// ~170 incl. AGPRs; this schedule peaks ~160):
// (a) LDS metadata arrays DELETED: lanes 0-31 hold their edge's record and
//     rel/dist/w in registers; consumers use __shfl (20 bpermutes/tile).
// (b) row gathers vR(t+1): issued before GEMM2, packed to bf16 (pkR, 16
//     regs) at end of iter, written to LDS wait-free at next tile top —
//     ~1000cy coverage for the random (L3-ish) row reads.
// (c) col gathers vC(t): issued at tile top, consumed between GEMM1's
//     kt{0,1} and kt{2,3} halves (~300cy cover; cols sorted -> L1/L2-hot).
//     kt accumulation order unchanged.
// (d) srec(t+1) covered by GEMM1; posw(t+1) covered by GEMM2 (waited at
//     next loop top where meta is derived).
// kt loops stay unroll(1) (anti-spill, r3-r5 lesson).
__global__ __launch_bounds__(256, 3) void node_kernel(
    const float* __restrict__ x, const unsigned char* __restrict__ ws,
    float* __restrict__ out) {
  __shared__ uint4 sFeat[2048];                    // 32 KB B-operand frags
  __shared__ __align__(16) float sAccX[NB * 68];   // 17 KB; cols 64..66 = pos acc

  const int tid = threadIdx.x;
  const int lane = tid & 63;
  const int wave = tid >> 6;
  const int q = lane >> 4;    // edge-slot subrow for gathers / acc quad
  const int nn = lane & 15;   // k-quad for gathers / acc column
  const int base = blockIdx.x * NB;
  const int et0 = wave * 2;
  const int W32 = wave * 32;

  const int* off = (const int*)(ws + WS_OFF);
  const unsigned int* srec = (const unsigned int*)(ws + WS_SREC);
  const uint4* wx1f = (const uint4*)(ws + WS_WX1);
  const uint4* wx2f = (const uint4*)(ws + WS_WX2);
  const float* misc = (const float*)(ws + WS_MISC);
  const float* posw = (const float*)(ws + WS_POSW);

  const int e0 = off[base];
  const int e1 = off[base + NB];

  // ---- prologue: tile-0 record + row gathers + posw (cold, once)
  unsigned int prec = 0;
  if (lane < 32) {
    int e = e0 + W32 + lane;
    e = e < EDGES ? e : EDGES - 1;
    prec = srec[e];
  }
  unsigned int rec[8];
#pragma unroll
  for (int i = 0; i < 8; ++i) rec[i] = __shfl(prec, i * 4 + q);

  float4 vR[8];
#pragma unroll
  for (int i = 0; i < 8; ++i)
    vR[i] = *(const float4*)(x + (size_t)(rec[i] & 0x1FFFFu) * 64 + nn * 4);

  float4 pR = {0.f, 0.f, 0.f, 0.f}, pC = {0.f, 0.f, 0.f, 0.f};
  if (lane < 32) {
    const int r = (int)(prec & 0x1FFFFu);
    int c = base + (int)(prec >> 17);
    c = c < NODES ? c : NODES - 1;
    pR = *(const float4*)(posw + 4 * (size_t)r);
    pC = *(const float4*)(posw + 4 * (size_t)c);
  }

  for (int i = tid; i < NB * 68; i += 256) sAccX[i] = 0.f;

  u32x2 pkR[8];
#pragma unroll
  for (int i = 0; i < 8; ++i) {
    pkR[i][0] = cvtpk2bf(vR[i].x, vR[i].y);
    pkR[i][1] = cvtpk2bf(vR[i].z, vR[i].w);
  }
  __syncthreads();  // sAccX ready before any wave's first lds_add

  const floatx4 fzero = {0.f, 0.f, 0.f, 0.f};
  float mw = 0.f, mr0 = 0.f, mr1 = 0.f, mr2 = 0.f, md = 0.f;

#pragma unroll 1
  for (int t0 = e0; t0 < e1; t0 += ET) {
    // ---- meta for this tile (holder lanes 0-31; waits posw issued last iter)
    mw = pR.w;
    mr0 = pR.x - pC.x;
    mr1 = pR.y - pC.y;
    mr2 = pR.z - pC.z;
    md = mr0 * mr0 + mr1 * mr1 + mr2 * mr2;

    // ---- issue col gathers (sorted cols -> L1/L2-hot; cover = GEMM1 kt0,1)
    float4 vC[8];
#pragma unroll
    for (int i = 0; i < 8; ++i)
      vC[i] = *(const float4*)(x + (size_t)(base + (int)(rec[i] >> 17)) * 64 + nn * 4);

    // ---- prefetch next tile's srec (cover = GEMM1)
    unsigned int rcN = 0;
    if (lane < 32) {
      int e = t0 + ET + W32 + lane;
      e = e < EDGES ? e : EDGES - 1;
      rcN = srec[e];
    }

    // ---- write row half (prepacked last iter: wait-free LDS writes)
#pragma unroll
    for (int i = 0; i < 8; ++i) {
      const int s = W32 + i * 4 + q;
      const int kt = nn >> 3;  // 0,1
      const int fl = (((nn >> 1) & 3) << 4) | (s & 15);
      *((u32x2*)&sFeat[((s >> 4) * 4 + kt) * 64 + fl] + (nn & 1)) = pkR[i];
    }

    // ---- GEMM1 kt 0,1 (row features)
    floatx4 acc1[2][8];
#pragma unroll
    for (int m = 0; m < 2; ++m)
#pragma unroll
      for (int j = 0; j < 8; ++j) acc1[m][j] = fzero;
#pragma unroll 1
    for (int kt = 0; kt < 2; ++kt) {
      const short8 b0 = __builtin_bit_cast(short8, sFeat[((et0 + 0) * 4 + kt) * 64 + lane]);
      const short8 b1 = __builtin_bit_cast(short8, sFeat[((et0 + 1) * 4 + kt) * 64 + lane]);
#pragma unroll
      for (int jt = 0; jt < 8; ++jt) {
        const short8 a = __builtin_bit_cast(short8, wx1f[(kt * 8 + jt) * 64 + lane]);
        acc1[0][jt] = MFMA(a, b0, acc1[0][jt]);
        acc1[1][jt] = MFMA(a, b1, acc1[1][jt]);
      }
    }

    // ---- write col half (vC mostly landed under GEMM1 kt0,1)
#pragma unroll
    for (int i = 0; i < 8; ++i) {
      const int s = W32 + i * 4 + q;
      const int kt = 2 | (nn >> 3);  // 2,3
      const int fl = (((nn >> 1) & 3) << 4) | (s & 15);
      u32x2 d;
      d[0] = cvtpk2bf(vC[i].x, vC[i].y);
      d[1] = cvtpk2bf(vC[i].z, vC[i].w);
      *((u32x2*)&sFeat[((s >> 4) * 4 + kt) * 64 + fl] + (nn & 1)) = d;
    }

    // ---- GEMM1 kt 2,3 (col features)
#pragma unroll 1
    for (int kt = 2; kt < 4; ++kt) {
      const short8 b0 = __builtin_bit_cast(short8, sFeat[((et0 + 0) * 4 + kt) * 64 + lane]);
      const short8 b1 = __builtin_bit_cast(short8, sFeat[((et0 + 1) * 4 + kt) * 64 + lane]);
#pragma unroll
      for (int jt = 0; jt < 8; ++jt) {
        const short8 a = __builtin_bit_cast(short8, wx1f[(kt * 8 + jt) * 64 + lane]);
        acc1[0][jt] = MFMA(a, b0, acc1[0][jt]);
        acc1[1][jt] = MFMA(a, b1, acc1[1][jt]);
      }
    }

    // ---- epilogue 1 (dist via shuffle; h overwrites sFeat rows)
#pragma unroll
    for (int m = 0; m < 2; ++m) {
      const int etG = et0 + m;
      const float dist = __shfl(md, m * 16 + nn);
#pragma unroll
      for (int jt = 0; jt < 8; ++jt) {
        const float4 bx = *(const float4*)(misc + 0 + jt * 16 + q * 4);
        const float4 wd = *(const float4*)(misc + 456 + jt * 16 + q * 4);
        const unsigned int h01 = cvtpk2bf(fast_silu(acc1[m][jt][0] + bx.x + dist * wd.x),
                                          fast_silu(acc1[m][jt][1] + bx.y + dist * wd.y));
        const unsigned int h23 = cvtpk2bf(fast_silu(acc1[m][jt][2] + bx.z + dist * wd.z),
                                          fast_silu(acc1[m][jt][3] + bx.w + dist * wd.w));
        const int j0 = jt * 16 + q * 4;
        const int kt2 = j0 >> 5;
        const int lane2 = (((j0 & 31) >> 3) << 4) | nn;
        const int byteoff = (j0 & 7) << 1;
        uint2* dst = (uint2*)((char*)sFeat +
                              (((size_t)((etG * 4 + kt2) * 64 + lane2)) << 4) + byteoff);
        *dst = make_uint2(h01, h23);
      }
    }

    // ---- next-tile posw + row-gather issue (cover = GEMM2 + epilogue2)
    if (lane < 32) {
      const int r = (int)(rcN & 0x1FFFFu);
      int c = base + (int)(rcN >> 17);
      c = c < NODES ? c : NODES - 1;
      pR = *(const float4*)(posw + 4 * (size_t)r);
      pC = *(const float4*)(posw + 4 * (size_t)c);
    }
#pragma unroll
    for (int i = 0; i < 8; ++i) rec[i] = __shfl(rcN, i * 4 + q);
#pragma unroll
    for (int i = 0; i < 8; ++i)
      vR[i] = *(const float4*)(x + (size_t)(rec[i] & 0x1FFFFu) * 64 + nn * 4);

    // ---- GEMM2 + merged segmented-scan scatter epilogue
    {
      floatx4 acc2[2][4];
#pragma unroll
      for (int m = 0; m < 2; ++m)
#pragma unroll
        for (int it = 0; it < 4; ++it) acc2[m][it] = fzero;
#pragma unroll 1
      for (int kt = 0; kt < 4; ++kt) {
        const short8 b0 = __builtin_bit_cast(short8, sFeat[((et0 + 0) * 4 + kt) * 64 + lane]);
        const short8 b1 = __builtin_bit_cast(short8, sFeat[((et0 + 1) * 4 + kt) * 64 + lane]);
#pragma unroll
        for (int it = 0; it < 4; ++it) {
          const short8 a = __builtin_bit_cast(short8, wx2f[(kt * 4 + it) * 64 + lane]);
          acc2[0][it] = MFMA(a, b0, acc2[0][it]);
          acc2[1][it] = MFMA(a, b1, acc2[1][it]);
        }
      }
#pragma unroll
      for (int m = 0; m < 2; ++m) {
        const int sl = m * 16 + nn;  // slot within wave's 32 edges (= src lane)
        const bool vE = (t0 + W32 + sl) < e1;
        int lcv = (int)(__shfl(prec, sl) >> 17);
        if (!vE) lcv = -1 - nn;  // singleton segments for invalid lanes
        // unconditional DPPs (convergent!) then bitwise combines:
        const int k1 = dpp_i<0x111>(lcv);
        const int k2 = dpp_i<0x112>(lcv);
        const int k4 = dpp_i<0x114>(lcv);
        const int k8 = dpp_i<0x118>(lcv);
        const int kn = dpp_i<0x101>(lcv);
        const bool m1 = (nn >= 1) & (k1 == lcv);
        const bool m2 = (nn >= 2) & (k2 == lcv);
        const bool m4 = (nn >= 4) & (k4 == lcv);
        const bool m8 = (nn >= 8) & (k8 == lcv);
        const bool tail = vE & ((nn == 15) | (kn != lcv));

        // pos update (meta via shuffles from holder lanes)
        const float wv = __shfl(mw, sl);
        const float r0 = __shfl(mr0, sl);
        const float r1 = __shfl(mr1, sl);
        const float r2 = __shfl(mr2, sl);
        float p0 = segscan(wv * r0, m1, m2, m4, m8);
        float p1 = segscan(wv * r1, m1, m2, m4, m8);
        float p2 = segscan(wv * r2, m1, m2, m4, m8);
        if (tail && q == 0) {
          float* ap = sAccX + lcv * 68 + 64;  // pos acc lives in the pad
          lds_add(ap + 0, p0);
          lds_add(ap + 1, p1);
          lds_add(ap + 2, p2);
        }
#pragma unroll
        for (int it = 0; it < 4; ++it) {
          const float4 b2 = *(const float4*)(misc + 128 + it * 16 + q * 4);
          float v0 = segscan(acc2[m][it][0] + b2.x, m1, m2, m4, m8);
          float v1 = segscan(acc2[m][it][1] + b2.y, m1, m2, m4, m8);
          float v2 = segscan(acc2[m][it][2] + b2.z, m1, m2, m4, m8);
          float v3 = segscan(acc2[m][it][3] + b2.w, m1, m2, m4, m8);
          if (tail) {
            float* arow = sAccX + lcv * 68;
            const int i0 = it * 16 + q * 4;
            lds_add(arow + i0 + 0, v0);
            lds_add(arow + i0 + 1, v1);
            lds_add(arow + i0 + 2, v2);
            lds_add(arow + i0 + 3, v3);
          }
        }
      }
    }

    // ---- pack next tile's rows (vR landed under GEMM2); rotate record
#pragma unroll
    for (int i = 0; i < 8; ++i) {
      pkR[i][0] = cvtpk2bf(vR[i].x, vR[i].y);
      pkR[i][1] = cvtpk2bf(vR[i].z, vR[i].w);
    }
    prec = rcN;
  }
  __syncthreads();  // all waves' LDS-atomic accumulates done

  // ---- final coalesced stores (no global atomics)
  {
    const int n = base + (tid >> 2);
    if (n < NODES) {
      const int c0 = (tid & 3) * 16;
      float* orow = out + (size_t)n * 64 + c0;
      const float* arow = sAccX + (tid >> 2) * 68 + c0;
#pragma unroll
      for (int j = 0; j < 16; j += 4) *(float4*)(orow + j) = *(const float4*)(arow + j);
    }
    if (tid < 192) {
      const int idx = base * 3 + tid;
      if (idx < NODES * 3)
        out[(size_t)NODES * 64 + idx] = sAccX[(tid / 3) * 68 + 64 + (tid % 3)];
    }
  }
}

extern "C" void kernel_launch(void* const* d_in, const int* in_sizes, int n_in,
                              void* d_out, int out_size, void* d_ws, size_t ws_size,
                              hipStream_t stream) {
  (void)in_sizes; (void)n_in; (void)ws_size; (void)out_size;
  const float* x = (const float*)d_in[0];
  const float* pos = (const float*)d_in[1];
  const int* ei = (const int*)d_in[2];
  const float* Wx1 = (const float*)d_in[3];
  const float* bx1 = (const float*)d_in[4];
  const float* Wx2 = (const float*)d_in[5];
  const float* bx2 = (const float*)d_in[6];
  const float* Wp1 = (const float*)d_in[7];
  const float* bp1 = (const float*)d_in[8];
  const float* Wp2 = (const float*)d_in[9];
  const float* bp2 = (const float*)d_in[10];
  float* out = (float*)d_out;
  unsigned char* ws = (unsigned char*)d_ws;

  int* counts = (int*)(ws + WS_CNT);   // aliased with cursor (scan3 rewrites)
  int* cursor = (int*)(ws + WS_CNT);
  int* off = (int*)(ws + WS_OFF);
  int* tmp = (int*)(ws + WS_TMP);      // aliased with srec (dies before scatter)
  int* bsum = (int*)(ws + WS_BSUM);
  unsigned int* srec = (unsigned int*)(ws + WS_SREC);

  prep_kernel<<<16, 256, 0, stream>>>(Wx1, Wx2, Wp1, bx1, bx2, bp1, Wp2, bp2, ws);
  wpos_kernel<<<NBW, 256, 0, stream>>>(x, pos, ws);
  const int eb = (EDGES + 255) / 256;
  hist_kernel<<<eb, 256, 0, stream>>>(ei, counts);
  scan1_kernel<<<SCB, 1024, 0, stream>>>(counts, tmp, bsum);
  scan3_kernel<<<SCB, 1024, 0, stream>>>(counts, tmp, bsum, off, cursor);
  scatter_kernel<<<eb, 256, 0, stream>>>(ei, cursor, srec);
  node_kernel<<<NBLK, 256, 0, stream>>>(x, ws, out);
}